// Round 1
// baseline (318.548 us; speedup 1.0000x reference)
//
#include <hip/hip_runtime.h>
#include <math.h>

// EngramGating: B=16, S=16384, H=4, D=K=32. ntok = B*S = 262144.
// Layout A: half-wave (32 lanes) = one token's k dimension; wave handles
// 8 tokens/iter (4 per half-wave) so weight LDS reads amortize.
// Weights in LDS as [dp][h*32+k][2] (d-pair interleaved -> ds_read_b64,
// bank = 2k%32 -> 2-way conflict = free per m136).

#define GRID    1024
#define EPS32   3.814697265625e-06f   // 32 * FLT_EPSILON
#define SQRT32  5.656854249492380f
#define LOG2E   1.4426950408889634f

__global__ __launch_bounds__(256) void engram_kernel(
    const float* __restrict__ emb,   // [ntok,32]
    const float* __restrict__ hid,   // [ntok,4,32]
    const float* __restrict__ Wv,    // [32,32]
    const float* __restrict__ bv,    // [32]
    const float* __restrict__ Wk,    // [4,32,32]
    const float* __restrict__ bk,    // [4,32]
    const float* __restrict__ g1,    // [4,32]
    const float* __restrict__ g2,    // [4,32]
    float* __restrict__ out,         // [ntok,4,32]
    int ntok)
{
    // Wl: 16 d-pairs x 160 channels (h*32+k for Wk, 128+k for Wv) x 2 (d parity)
    __shared__ float Wl[16 * 160 * 2];          // 20480 B
    __shared__ float Elds[4][8 * 32];           // per-wave 8 token rows, 4096 B

    const int tid  = threadIdx.x;
    const int wave = tid >> 6;
    const int lane = tid & 63;
    const int k    = lane & 31;
    const int h2   = lane >> 5;        // which half-wave
    const int mytok = h2 * 4;          // local token base for this half

    // ---- stage weights (transpose) ----
    for (int i = tid; i < 5120; i += 256) {
        int d = i & 31;
        int r = i >> 5;                // 0..159: r<128 -> Wk ch, else Wv ch
        float v = (r < 128) ? Wk[r * 32 + d] : Wv[(r - 128) * 32 + d];
        Wl[(((d >> 1) * 160 + r) << 1) | (d & 1)] = v;
    }
    // per-lane constants (indexed by k)
    float bk_r[4], g12_r[4];
    #pragma unroll
    for (int h = 0; h < 4; ++h) {
        bk_r[h]  = bk[h * 32 + k];
        g12_r[h] = g1[h * 32 + k] * g2[h * 32 + k];
    }
    const float bv_r = bv[k];
    __syncthreads();

    const int tokens_per_block = ntok / GRID;        // 256
    const int iters = tokens_per_block >> 5;         // 8 (32 tokens/block-iter)
    const int blk_base = blockIdx.x * tokens_per_block;
    const float2* __restrict__ W2 = (const float2*)Wl;

    for (int it = 0; it < iters; ++it) {
        const int tb = blk_base + it * 32 + wave * 8;   // this wave's 8 tokens

        // stage emb rows for 8 tokens: 1024 contiguous bytes, one float4/lane
        {
            const float4 ev = *(const float4*)(emb + tb * 32 + lane * 4);
            *(float4*)&Elds[wave][lane * 4] = ev;
        }
        // prefetch hidden (q) early to overlap with the matvec loop
        float q[4][4];
        #pragma unroll
        for (int t = 0; t < 4; ++t)
            #pragma unroll
            for (int h = 0; h < 4; ++h)
                q[t][h] = hid[(tb + mytok + t) * 128 + h * 32 + k];

        // same-wave producer->consumer on Elds: drain LDS writes
        __asm__ volatile("s_waitcnt lgkmcnt(0)" ::: "memory");

        float kacc[4][4] = {{0.f,0.f,0.f,0.f},{0.f,0.f,0.f,0.f},
                            {0.f,0.f,0.f,0.f},{0.f,0.f,0.f,0.f}};
        float vacc[4] = {0.f, 0.f, 0.f, 0.f};

        #pragma unroll 8
        for (int dp = 0; dp < 16; ++dp) {
            const float2 w0 = W2[dp * 160 + k];
            const float2 w1 = W2[dp * 160 + 32 + k];
            const float2 w2 = W2[dp * 160 + 64 + k];
            const float2 w3 = W2[dp * 160 + 96 + k];
            const float2 wv = W2[dp * 160 + 128 + k];
            #pragma unroll
            for (int t = 0; t < 4; ++t) {
                const float2 e2 = *(const float2*)&Elds[wave][(mytok + t) * 32 + 2 * dp];
                kacc[t][0] = fmaf(e2.y, w0.y, fmaf(e2.x, w0.x, kacc[t][0]));
                kacc[t][1] = fmaf(e2.y, w1.y, fmaf(e2.x, w1.x, kacc[t][1]));
                kacc[t][2] = fmaf(e2.y, w2.y, fmaf(e2.x, w2.x, kacc[t][2]));
                kacc[t][3] = fmaf(e2.y, w3.y, fmaf(e2.x, w3.x, kacc[t][3]));
                vacc[t]    = fmaf(e2.y, wv.y, fmaf(e2.x, wv.x, vacc[t]));
            }
        }

        #pragma unroll
        for (int t = 0; t < 4; ++t) {
            vacc[t] += bv_r;
            float gate[4];
            #pragma unroll
            for (int h = 0; h < 4; ++h) {
                const float kk = kacc[t][h] + bk_r[h];
                float A  = kk * kk;                         // sum key^2
                float Bq = q[t][h] * q[t][h];               // sum q^2
                float C  = kk * q[t][h] * g12_r[h];         // sum key*q*g1*g2
                #pragma unroll
                for (int off = 16; off; off >>= 1) {
                    A  += __shfl_xor(A,  off, 32);
                    Bq += __shfl_xor(Bq, off, 32);
                    C  += __shfl_xor(C,  off, 32);
                }
                // gate_pre = C*sqrt(32)*rsqrt(A+32eps)*rsqrt(B+32eps)
                float g = C * SQRT32 * __builtin_amdgcn_rsqf(A + EPS32)
                                     * __builtin_amdgcn_rsqf(Bq + EPS32);
                float r = copysignf(sqrtf(fmaxf(fabsf(g), 1e-6f)), g);
                gate[h] = 1.0f / (1.0f + __builtin_amdgcn_exp2f(-r * LOG2E));
            }
            const int ob = (tb + mytok + t) * 128 + k;
            #pragma unroll
            for (int h = 0; h < 4; ++h)
                out[ob + h * 32] = gate[h] * vacc[t];
        }
    }
}

extern "C" void kernel_launch(void* const* d_in, const int* in_sizes, int n_in,
                              void* d_out, int out_size, void* d_ws, size_t ws_size,
                              hipStream_t stream) {
    const float* emb = (const float*)d_in[0];
    const float* hid = (const float*)d_in[1];
    const float* Wv  = (const float*)d_in[2];
    const float* bv  = (const float*)d_in[3];
    const float* Wk  = (const float*)d_in[4];
    const float* bk  = (const float*)d_in[5];
    const float* g1  = (const float*)d_in[6];
    const float* g2  = (const float*)d_in[7];
    float* out = (float*)d_out;
    const int ntok = in_sizes[0] / 32;   // 262144
    engram_kernel<<<GRID, 256, 0, stream>>>(emb, hid, Wv, bv, Wk, bk, g1, g2,
                                            out, ntok);
}

// Round 5
// 284.790 us; speedup vs baseline: 1.1185x; 1.1185x over previous
//
#include <hip/hip_runtime.h>
#include <math.h>

// EngramGating: B=16, S=16384, H=4, D=K=32. ntok = B*S = 262144.
// Half-wave (32 lanes) = one token's k dimension; wave handles 8 tokens/iter.
// R5 (= R4 resubmitted; R4 was an infra failure, never ran):
// DPP reduction via __builtin_amdgcn_update_dpp (compiler inserts the
// required DPP wait-states; raw asm v_add_f32_dpp in R3 hit the VALU->DPP
// read-after-write hazard -> stale reads -> absmax 0.176). One ds_swizzle
// per gate broadcasts lane31/63 to its half-wave. Grid 2048 for TLP.

#define GRID    2048
#define EPS32   3.814697265625e-06f   // 32 * FLT_EPSILON
#define SQRT32  5.656854249492380f
#define LOG2E   1.4426950408889634f

// DPP ctrl encodings (gfx9): row_shr:N = 0x110|N, row_bcast:15 = 0x142
#define DPP_ADD(x, ctrl) \
    x += __int_as_float(__builtin_amdgcn_update_dpp( \
        0, __float_as_int(x), ctrl, 0xF, 0xF, true))

// After this, lane31 = sum(lanes 0..31), lane63 = sum(lanes 32..63).
__device__ __forceinline__ float half_sum_to_lane31(float x) {
    DPP_ADD(x, 0x111);   // row_shr:1
    DPP_ADD(x, 0x112);   // row_shr:2
    DPP_ADD(x, 0x114);   // row_shr:4
    DPP_ADD(x, 0x118);   // row_shr:8  -> lane15 of each 16-row = row sum
    DPP_ADD(x, 0x142);   // row_bcast:15 -> next row adds prev row's lane15
    return x;
}

__global__ __launch_bounds__(256) void engram_kernel(
    const float* __restrict__ emb,   // [ntok,32]
    const float* __restrict__ hid,   // [ntok,4,32]
    const float* __restrict__ Wv,    // [32,32]
    const float* __restrict__ bv,    // [32]
    const float* __restrict__ Wk,    // [4,32,32]
    const float* __restrict__ bk,    // [4,32]
    const float* __restrict__ g1,    // [4,32]
    const float* __restrict__ g2,    // [4,32]
    float* __restrict__ out,         // [ntok,4,32]
    int ntok)
{
    // Wl: 16 d-pairs x 160 channels (h*32+k for Wk, 128+k for Wv) x 2 (d parity)
    __shared__ float Wl[16 * 160 * 2];          // 20480 B
    __shared__ float Elds[4][8 * 32];           // per-wave 8 token rows, 4096 B

    const int tid  = threadIdx.x;
    const int wave = tid >> 6;
    const int lane = tid & 63;
    const int k    = lane & 31;
    const int h2   = lane >> 5;        // which half-wave
    const int mytok = h2 * 4;          // local token base for this half

    // ---- stage weights (transpose) ----
    for (int i = tid; i < 5120; i += 256) {
        int d = i & 31;
        int r = i >> 5;                // 0..159: r<128 -> Wk ch, else Wv ch
        float v = (r < 128) ? Wk[r * 32 + d] : Wv[(r - 128) * 32 + d];
        Wl[(((d >> 1) * 160 + r) << 1) | (d & 1)] = v;
    }
    // per-lane constants (indexed by k)
    float bk_r[4], g12_r[4];
    #pragma unroll
    for (int h = 0; h < 4; ++h) {
        bk_r[h]  = bk[h * 32 + k];
        g12_r[h] = g1[h * 32 + k] * g2[h * 32 + k];
    }
    const float bv_r = bv[k];
    __syncthreads();

    const int tokens_per_block = ntok / GRID;        // 128
    const int iters = tokens_per_block >> 5;         // 4 (32 tokens/block-iter)
    const int blk_base = blockIdx.x * tokens_per_block;
    const float2* __restrict__ W2 = (const float2*)Wl;

    for (int it = 0; it < iters; ++it) {
        const int tb = blk_base + it * 32 + wave * 8;   // this wave's 8 tokens

        // stage emb rows for 8 tokens: 1024 contiguous bytes, one float4/lane
        {
            const float4 ev = *(const float4*)(emb + tb * 32 + lane * 4);
            *(float4*)&Elds[wave][lane * 4] = ev;
        }
        // prefetch hidden (q) early to overlap with the matvec loop
        float q[4][4];
        #pragma unroll
        for (int t = 0; t < 4; ++t)
            #pragma unroll
            for (int h = 0; h < 4; ++h)
                q[t][h] = hid[(tb + mytok + t) * 128 + h * 32 + k];

        // same-wave producer->consumer on Elds: drain LDS writes
        __asm__ volatile("s_waitcnt lgkmcnt(0)" ::: "memory");

        float kacc[4][4] = {{0.f,0.f,0.f,0.f},{0.f,0.f,0.f,0.f},
                            {0.f,0.f,0.f,0.f},{0.f,0.f,0.f,0.f}};
        float vacc[4] = {0.f, 0.f, 0.f, 0.f};

        #pragma unroll 8
        for (int dp = 0; dp < 16; ++dp) {
            const float2 w0 = W2[dp * 160 + k];
            const float2 w1 = W2[dp * 160 + 32 + k];
            const float2 w2 = W2[dp * 160 + 64 + k];
            const float2 w3 = W2[dp * 160 + 96 + k];
            const float2 wv = W2[dp * 160 + 128 + k];
            #pragma unroll
            for (int t = 0; t < 4; ++t) {
                const float2 e2 = *(const float2*)&Elds[wave][(mytok + t) * 32 + 2 * dp];
                kacc[t][0] = fmaf(e2.y, w0.y, fmaf(e2.x, w0.x, kacc[t][0]));
                kacc[t][1] = fmaf(e2.y, w1.y, fmaf(e2.x, w1.x, kacc[t][1]));
                kacc[t][2] = fmaf(e2.y, w2.y, fmaf(e2.x, w2.x, kacc[t][2]));
                kacc[t][3] = fmaf(e2.y, w3.y, fmaf(e2.x, w3.x, kacc[t][3]));
                vacc[t]    = fmaf(e2.y, wv.y, fmaf(e2.x, wv.x, vacc[t]));
            }
        }

        #pragma unroll
        for (int t = 0; t < 4; ++t) {
            vacc[t] += bv_r;
            float gate[4];
            #pragma unroll
            for (int h = 0; h < 4; ++h) {
                const float kk = kacc[t][h] + bk_r[h];
                float A  = kk * kk;                         // -> sum key^2
                float Bq = q[t][h] * q[t][h];               // -> sum q^2
                float C  = kk * q[t][h] * g12_r[h];         // -> sum key*q*g1*g2
                A  = half_sum_to_lane31(A);
                Bq = half_sum_to_lane31(Bq);
                C  = half_sum_to_lane31(C);
                // valid only on lanes 31/63; other lanes compute garbage
                float g = C * SQRT32 * __builtin_amdgcn_rsqf(A + EPS32)
                                     * __builtin_amdgcn_rsqf(Bq + EPS32);
                float r = copysignf(sqrtf(fmaxf(fabsf(g), 1e-6f)), g);
                float gl = 1.0f / (1.0f + __builtin_amdgcn_exp2f(-r * LOG2E));
                // broadcast lane31 -> lanes 0..31, lane63 -> lanes 32..63
                // ds_swizzle bit mode: and=0x1F, or=0x1F, xor=0 -> lane (i|31)
                gate[h] = __int_as_float(
                    __builtin_amdgcn_ds_swizzle(__float_as_int(gl), 0x3FF));
            }
            const int ob = (tb + mytok + t) * 128 + k;
            #pragma unroll
            for (int h = 0; h < 4; ++h)
                out[ob + h * 32] = gate[h] * vacc[t];
        }
    }
}

extern "C" void kernel_launch(void* const* d_in, const int* in_sizes, int n_in,
                              void* d_out, int out_size, void* d_ws, size_t ws_size,
                              hipStream_t stream) {
    const float* emb = (const float*)d_in[0];
    const float* hid = (const float*)d_in[1];
    const float* Wv  = (const float*)d_in[2];
    const float* bv  = (const float*)d_in[3];
    const float* Wk  = (const float*)d_in[4];
    const float* bk  = (const float*)d_in[5];
    const float* g1  = (const float*)d_in[6];
    const float* g2  = (const float*)d_in[7];
    float* out = (float*)d_out;
    const int ntok = in_sizes[0] / 32;   // 262144
    engram_kernel<<<GRID, 256, 0, stream>>>(emb, hid, Wv, bv, Wk, bk, g1, g2,
                                            out, ntok);
}